// Round 1
// baseline (320.167 us; speedup 1.0000x reference)
//
#include <hip/hip_runtime.h>

// out[b,c,h,w] = block_switch[h/8, w/8] ? -1.0f : image[b,c,h,w]
// image: [64, 3, 512, 512] fp32 ; block_switch: [64, 64] (bool -> int32 per harness)
//
// One float4 per thread. W = 512 floats per row = 128 float4 per row.
// A float4 starts at w = 4*k; 4k and 4k+3 share the same w/8 block
// (4k % 8 is 0 or 4, so the group never straddles an 8-boundary) ->
// a single mask lookup covers the whole float4.

#define H 512
#define W 512
#define BLK 8
#define MASK_W (W / BLK)   // 64

__global__ __launch_bounds__(256) void grid_crop_kernel(
    const float4* __restrict__ img,
    const int* __restrict__ mask,
    float4* __restrict__ out,
    int n4)
{
    int idx = blockIdx.x * blockDim.x + threadIdx.x;
    if (idx >= n4) return;

    int elem = idx << 2;                 // flat float index
    int w = elem & (W - 1);              // 0..511
    int h = (elem >> 9) & (H - 1);       // 0..511  (W == 512 == 2^9)
    int m = mask[(h >> 3) * MASK_W + (w >> 3)];

    float4 v;
    if (m) {
        v = make_float4(-1.0f, -1.0f, -1.0f, -1.0f);
    } else {
        v = img[idx];                    // only fetch unmasked data
    }
    out[idx] = v;
}

extern "C" void kernel_launch(void* const* d_in, const int* in_sizes, int n_in,
                              void* d_out, int out_size, void* d_ws, size_t ws_size,
                              hipStream_t stream) {
    const float4* img  = (const float4*)d_in[0];
    const int*    mask = (const int*)d_in[1];
    float4*       out  = (float4*)d_out;

    int n4 = out_size >> 2;              // 64*3*512*512 / 4 = 12,582,912
    int block = 256;
    int grid = (n4 + block - 1) / block; // 49,152 blocks

    grid_crop_kernel<<<grid, block, 0, stream>>>(img, mask, out, n4);
}